// Round 6
// baseline (175.980 us; speedup 1.0000x reference)
//
#include <hip/hip_runtime.h>

#define N_   2
#define C_   256
#define H_   55
#define W_   128
#define HW_  (H_ * W_)      // 7040
#define NPIX (N_ * HW_)     // 14080
#define PB   16             // pixels per block
#define PW   4              // pixels per wave
#define NBLK (NPIX / PB)    // 880 = 8 * 110
#define BPX  (NBLK / 8)     // 110 blocks per XCD band
#define F1LD 260            // padded leading dim

#define OFF_CV  0
#define OFF_VAL (NPIX * 25)          // 352000
#define OFF_XY  (OFF_VAL + NPIX)     // 366080

// ---------------------------------------------------------------------------
// Transpose f2 only: [C, HW] -> [HW, C] per n.  blockIdx.z = n.
// ---------------------------------------------------------------------------
__global__ __launch_bounds__(256) void transpose_f2(const float* __restrict__ f2,
                                                    float* __restrict__ f2t) {
    __shared__ float tile[64][65];
    const int n = blockIdx.z;
    const float* __restrict__ src = f2 + (size_t)n * C_ * HW_;
    float* __restrict__ dst = f2t + (size_t)n * HW_ * C_;

    const int p0 = blockIdx.x * 64;
    const int c0 = blockIdx.y * 64;
    const int q = threadIdx.x & 15;
    const int r = threadIdx.x >> 4;

    #pragma unroll
    for (int rr = r; rr < 64; rr += 16) {
        const float4 v = *(const float4*)(src + (size_t)(c0 + rr) * HW_ + p0 + q * 4);
        tile[rr][q * 4 + 0] = v.x;
        tile[rr][q * 4 + 1] = v.y;
        tile[rr][q * 4 + 2] = v.z;
        tile[rr][q * 4 + 3] = v.w;
    }
    __syncthreads();

    #pragma unroll
    for (int j = 0; j < 4; ++j) {
        const int pr = r + 16 * j;
        float4 v;
        v.x = tile[q * 4 + 0][pr];
        v.y = tile[q * 4 + 1][pr];
        v.z = tile[q * 4 + 2][pr];
        v.w = tile[q * 4 + 3][pr];
        *(float4*)(dst + (size_t)(p0 + pr) * C_ + c0 + q * 4) = v;
    }
}

__device__ __forceinline__ float dot4(const float4 a, const float4 b) {
    return a.x * b.x + a.y * b.y + a.z * b.z + a.w * b.w;
}

// VALU-only 16-lane sum (DPP butterfly within a DPP row of 16 lanes).
__device__ __forceinline__ float dpp_add16(float x) {
    int v;
    v = __builtin_amdgcn_update_dpp(0, __float_as_int(x), 0xB1, 0xF, 0xF, true);  // quad_perm xor1
    x += __int_as_float(v);
    v = __builtin_amdgcn_update_dpp(0, __float_as_int(x), 0x4E, 0xF, 0xF, true);  // quad_perm xor2
    x += __int_as_float(v);
    v = __builtin_amdgcn_update_dpp(0, __float_as_int(x), 0x141, 0xF, 0xF, true); // row_half_mirror
    x += __int_as_float(v);
    v = __builtin_amdgcn_update_dpp(0, __float_as_int(x), 0x140, 0xF, 0xF, true); // row_mirror
    x += __int_as_float(v);
    return x;
}

// ---------------------------------------------------------------------------
// Main kernel: 16 consecutive pixels per block, 4 waves x 4 pixels.
// Per pixel: 9 passes x 4 samples, triple-buffered loads 2 passes ahead
// (clamped addresses, validity folded in at compute), per-lane partials D[9],
// all reductions deferred to a DPP butterfly after the load loop.
// ---------------------------------------------------------------------------
__global__ __launch_bounds__(256, 4) void costvol_kernel(const float* __restrict__ flow,
                                                         const float* __restrict__ f1,
                                                         const float* __restrict__ f2t,
                                                         float* __restrict__ out) {
    __shared__ float f1sh[PB][F1LD];
    __shared__ float Dsh[4][36];

    const int b    = blockIdx.x;
    const int xcd  = b & 7;
    const int kk   = b >> 3;
    const int pix0 = (xcd * BPX + kk) * PB;   // bijective; 1760-pixel bands per XCD
    const int n     = pix0 / HW_;
    const int prem0 = pix0 - n * HW_;
    const int h     = prem0 >> 7;
    const int w0    = prem0 & (W_ - 1);

    // Stage f1[*, pix0..pix0+15] coalesced (float4 across 4 consecutive pixels).
    {
        const int px4   = threadIdx.x & 3;
        const int cbase = threadIdx.x >> 2;
        #pragma unroll
        for (int it = 0; it < 4; ++it) {
            const int c = cbase + it * 64;
            const float4 v = *(const float4*)(f1 + ((size_t)n * C_ + c) * HW_ + prem0 + px4 * 4);
            f1sh[px4 * 4 + 0][c] = v.x;
            f1sh[px4 * 4 + 1][c] = v.y;
            f1sh[px4 * 4 + 2][c] = v.z;
            f1sh[px4 * 4 + 3][c] = v.w;
        }
    }
    __syncthreads();

    const int wv   = threadIdx.x >> 6;
    const int lane = threadIdx.x & 63;
    const int sgrp = lane >> 4;     // 0..3  sample slot within pass
    const int cgrp = lane & 15;     // 0..15 channel chunk

    // Per-pass window offsets (depend only on sgrp) — hoisted out of pixel loop.
    int lyv[9], lxv[9];
    #pragma unroll
    for (int p = 0; p < 9; ++p) {
        const int s = p * 4 + sgrp;
        lyv[p] = s / 6;
        lxv[p] = s - 6 * lyv[p];
    }

    const float4* __restrict__ f2base = (const float4*)(f2t + (size_t)n * HW_ * C_);
    const float* __restrict__ flown   = flow + (size_t)n * 2 * HW_;

    for (int pp = 0; pp < PW; ++pp) {
        const int pl  = wv * PW + pp;
        const int pix = pix0 + pl;
        const int w   = w0 + pl;

        const float fx = flown[h * W_ + w];
        const float fy = flown[HW_ + h * W_ + w];
        const float cx = (float)w + fx;
        const float cy = (float)h + fy;
        const float x0f = floorf(cx), y0f = floorf(cy);
        const float wx = cx - x0f, wy = cy - y0f;
        const int ix0 = (int)x0f, iy0 = (int)y0f;

        const float* fr = &f1sh[pl][cgrp * 4];
        const float4 a0 = *(const float4*)(fr);
        const float4 a1 = *(const float4*)(fr + 64);
        const float4 a2 = *(const float4*)(fr + 128);
        const float4 a3 = *(const float4*)(fr + 192);

        float4 bbs[3][4];   // statically indexed after full unroll
        float  D[9];

#define ISSUE(p, slot) {                                                        \
            const int sy = iy0 - 2 + lyv[p];                                    \
            const int sx = ix0 - 2 + lxv[p];                                    \
            const int scy = min(max(sy, 0), H_ - 1);                            \
            const int scx = min(max(sx, 0), W_ - 1);                            \
            const float4* __restrict__ bp =                                     \
                f2base + (size_t)(scy * W_ + scx) * (C_ / 4) + cgrp;            \
            bbs[slot][0] = bp[0];  bbs[slot][1] = bp[16];                       \
            bbs[slot][2] = bp[32]; bbs[slot][3] = bp[48]; }

        ISSUE(0, 0)
        ISSUE(1, 1)
        #pragma unroll
        for (int p = 0; p < 9; ++p) {
            if (p < 7) ISSUE(p + 2, (p + 2) % 3)
            const int slot = p % 3;
            const int sy = iy0 - 2 + lyv[p];
            const int sx = ix0 - 2 + lxv[p];
            const bool vld = ((unsigned)sy < (unsigned)H_) && ((unsigned)sx < (unsigned)W_);
            const float part = dot4(a0, bbs[slot][0]) + dot4(a1, bbs[slot][1])
                             + dot4(a2, bbs[slot][2]) + dot4(a3, bbs[slot][3]);
            D[p] = vld ? part : 0.f;
        }
#undef ISSUE

        // Deferred reductions: 9 independent VALU-only DPP butterflies.
        #pragma unroll
        for (int p = 0; p < 9; ++p) {
            const float t = dpp_add16(D[p]);
            if (cgrp == 0) Dsh[wv][p * 4 + sgrp] = t;
        }
        __builtin_amdgcn_wave_barrier();   // Dsh writes before same-wave reads

        float cv = 0.f;
        if (lane < 25) {
            const int i = lane / 5, j = lane - i * 5;   // i -> dy, j -> dx
            const float D00 = Dsh[wv][i * 6 + j];
            const float D01 = Dsh[wv][i * 6 + j + 1];
            const float D10 = Dsh[wv][i * 6 + j + 6];
            const float D11 = Dsh[wv][i * 6 + j + 7];
            cv = (1.f - wx) * (1.f - wy) * D00 + wx * (1.f - wy) * D01
               + (1.f - wx) * wy * D10 + wx * wy * D11;
            out[OFF_CV + (size_t)pix * 25 + lane] = cv;
        }

        // WTA: max with first-occurrence tie-break (matches np/jnp argmax).
        float v  = (lane < 25) ? cv : -3.4e38f;
        int  idx = (lane < 25) ? lane : 25;
        #pragma unroll
        for (int off = 16; off >= 1; off >>= 1) {
            const float v2 = __shfl_down(v, off, 32);
            const int   i2 = __shfl_down(idx, off, 32);
            if (v2 > v || (v2 == v && i2 < idx)) { v = v2; idx = i2; }
        }
        if (lane == 0) {
            out[OFF_VAL + pix] = v;
            out[OFF_XY + pix]        = (float)(idx % 5);   // x
            out[OFF_XY + NPIX + pix] = (float)(idx / 5);   // y
        }
        __builtin_amdgcn_wave_barrier();   // next iter's Dsh writes stay behind reads
    }
}

// ---------------------------------------------------------------------------
extern "C" void kernel_launch(void* const* d_in, const int* in_sizes, int n_in,
                              void* d_out, int out_size, void* d_ws, size_t ws_size,
                              hipStream_t stream) {
    const float* flow = (const float*)d_in[0];
    const float* f1   = (const float*)d_in[1];
    const float* f2   = (const float*)d_in[2];
    float* out = (float*)d_out;

    float* f2t = (float*)d_ws;                       // [N, HW, C]

    transpose_f2<<<dim3(HW_ / 64, C_ / 64, N_), 256, 0, stream>>>(f2, f2t);
    costvol_kernel<<<dim3(NBLK), 256, 0, stream>>>(flow, f1, f2t, out);
}

// Round 7
// 103.677 us; speedup vs baseline: 1.6974x; 1.6974x over previous
//
#include <hip/hip_runtime.h>

#define N_   2
#define C_   256
#define H_   55
#define W_   128
#define HW_  (H_ * W_)      // 7040
#define NPIX (N_ * HW_)     // 14080
#define PB   16             // pixels per block
#define PW   4              // pixels per wave
#define NBLK (NPIX / PB)    // 880 = 8 * 110
#define BPX  (NBLK / 8)     // 110 blocks per XCD band
#define F1LD 260            // padded leading dim

#define OFF_CV  0
#define OFF_VAL (NPIX * 25)          // 352000
#define OFF_XY  (OFF_VAL + NPIX)     // 366080

// ---------------------------------------------------------------------------
// Transpose f2 only: [C, HW] -> [HW, C] per n.  blockIdx.z = n.
// ---------------------------------------------------------------------------
__global__ __launch_bounds__(256) void transpose_f2(const float* __restrict__ f2,
                                                    float* __restrict__ f2t) {
    __shared__ float tile[64][65];
    const int n = blockIdx.z;
    const float* __restrict__ src = f2 + (size_t)n * C_ * HW_;
    float* __restrict__ dst = f2t + (size_t)n * HW_ * C_;

    const int p0 = blockIdx.x * 64;
    const int c0 = blockIdx.y * 64;
    const int q = threadIdx.x & 15;
    const int r = threadIdx.x >> 4;

    #pragma unroll
    for (int rr = r; rr < 64; rr += 16) {
        const float4 v = *(const float4*)(src + (size_t)(c0 + rr) * HW_ + p0 + q * 4);
        tile[rr][q * 4 + 0] = v.x;
        tile[rr][q * 4 + 1] = v.y;
        tile[rr][q * 4 + 2] = v.z;
        tile[rr][q * 4 + 3] = v.w;
    }
    __syncthreads();

    #pragma unroll
    for (int j = 0; j < 4; ++j) {
        const int pr = r + 16 * j;
        float4 v;
        v.x = tile[q * 4 + 0][pr];
        v.y = tile[q * 4 + 1][pr];
        v.z = tile[q * 4 + 2][pr];
        v.w = tile[q * 4 + 3][pr];
        *(float4*)(dst + (size_t)(p0 + pr) * C_ + c0 + q * 4) = v;
    }
}

__device__ __forceinline__ float dot4(const float4 a, const float4 b) {
    return a.x * b.x + a.y * b.y + a.z * b.z + a.w * b.w;
}

// VALU-only 16-lane sum (DPP butterfly within a DPP row of 16 lanes).
__device__ __forceinline__ float dpp_add16(float x) {
    int v;
    v = __builtin_amdgcn_update_dpp(0, __float_as_int(x), 0xB1, 0xF, 0xF, true);  // quad_perm xor1
    x += __int_as_float(v);
    v = __builtin_amdgcn_update_dpp(0, __float_as_int(x), 0x4E, 0xF, 0xF, true);  // quad_perm xor2
    x += __int_as_float(v);
    v = __builtin_amdgcn_update_dpp(0, __float_as_int(x), 0x141, 0xF, 0xF, true); // row_half_mirror
    x += __int_as_float(v);
    v = __builtin_amdgcn_update_dpp(0, __float_as_int(x), 0x140, 0xF, 0xF, true); // row_mirror
    x += __int_as_float(v);
    return x;
}

// ---------------------------------------------------------------------------
// Main kernel: 16 consecutive pixels per block, 4 waves x 4 pixels.
// 3-deep software pipeline over the 9 passes, ALL buffers individually named
// float4 registers (no arrays anywhere -> no scratch). Clamped addresses,
// validity folded in at compute; reductions deferred to DPP butterflies.
// ---------------------------------------------------------------------------
__global__ __launch_bounds__(256) void costvol_kernel(const float* __restrict__ flow,
                                                      const float* __restrict__ f1,
                                                      const float* __restrict__ f2t,
                                                      float* __restrict__ out) {
    __shared__ float f1sh[PB][F1LD];
    __shared__ float Dsh[4][36];

    const int b    = blockIdx.x;
    const int xcd  = b & 7;
    const int kk   = b >> 3;
    const int pix0 = (xcd * BPX + kk) * PB;   // bijective; 1760-pixel bands per XCD
    const int n     = pix0 / HW_;
    const int prem0 = pix0 - n * HW_;
    const int h     = prem0 >> 7;
    const int w0    = prem0 & (W_ - 1);

    // Stage f1[*, pix0..pix0+15] coalesced (float4 across 4 consecutive pixels).
    {
        const int px4   = threadIdx.x & 3;
        const int cbase = threadIdx.x >> 2;
        #pragma unroll
        for (int it = 0; it < 4; ++it) {
            const int c = cbase + it * 64;
            const float4 v = *(const float4*)(f1 + ((size_t)n * C_ + c) * HW_ + prem0 + px4 * 4);
            f1sh[px4 * 4 + 0][c] = v.x;
            f1sh[px4 * 4 + 1][c] = v.y;
            f1sh[px4 * 4 + 2][c] = v.z;
            f1sh[px4 * 4 + 3][c] = v.w;
        }
    }
    __syncthreads();

    const int wv   = threadIdx.x >> 6;
    const int lane = threadIdx.x & 63;
    const int sgrp = lane >> 4;     // 0..3  sample slot within pass
    const int cgrp = lane & 15;     // 0..15 channel chunk

    // Per-pass window offsets (named scalars; depend only on sgrp).
    const int s0 = sgrp,      s1 = 4 + sgrp,  s2 = 8 + sgrp,  s3 = 12 + sgrp;
    const int s4 = 16 + sgrp, s5 = 20 + sgrp, s6 = 24 + sgrp, s7 = 28 + sgrp;
    const int s8 = 32 + sgrp;
    const int ly0 = s0 / 6, lx0 = s0 - 6 * ly0;
    const int ly1 = s1 / 6, lx1 = s1 - 6 * ly1;
    const int ly2 = s2 / 6, lx2 = s2 - 6 * ly2;
    const int ly3 = s3 / 6, lx3 = s3 - 6 * ly3;
    const int ly4 = s4 / 6, lx4 = s4 - 6 * ly4;
    const int ly5 = s5 / 6, lx5 = s5 - 6 * ly5;
    const int ly6 = s6 / 6, lx6 = s6 - 6 * ly6;
    const int ly7 = s7 / 6, lx7 = s7 - 6 * ly7;
    const int ly8 = s8 / 6, lx8 = s8 - 6 * ly8;

    const float4* __restrict__ f2base = (const float4*)(f2t + (size_t)n * HW_ * C_);
    const float* __restrict__ flown   = flow + (size_t)n * 2 * HW_;

    for (int pp = 0; pp < PW; ++pp) {
        const int pl  = wv * PW + pp;
        const int pix = pix0 + pl;
        const int w   = w0 + pl;

        const float fx = flown[h * W_ + w];
        const float fy = flown[HW_ + h * W_ + w];
        const float cx = (float)w + fx;
        const float cy = (float)h + fy;
        const float x0f = floorf(cx), y0f = floorf(cy);
        const float wx = cx - x0f, wy = cy - y0f;
        const int ix0 = (int)x0f, iy0 = (int)y0f;

        const float* fr = &f1sh[pl][cgrp * 4];
        const float4 a0 = *(const float4*)(fr);
        const float4 a1 = *(const float4*)(fr + 64);
        const float4 a2 = *(const float4*)(fr + 128);
        const float4 a3 = *(const float4*)(fr + 192);

        float4 A0, A1, A2, A3, B0, B1, B2, B3, C0, C1, C2, C3;

// clamped base pointer for pass offsets (LY,LX)
#define BPTR(LY, LX)                                                            \
    (f2base + (size_t)(min(max(iy0 - 2 + (LY), 0), H_ - 1) * W_ +               \
                       min(max(ix0 - 2 + (LX), 0), W_ - 1)) * (C_ / 4) + cgrp)
#define LDX(R0, R1, R2, R3, LY, LX) {                                           \
        const float4* __restrict__ bp = BPTR(LY, LX);                           \
        R0 = bp[0]; R1 = bp[16]; R2 = bp[32]; R3 = bp[48]; }
#define CMP(R0, R1, R2, R3, LY, LX)                                             \
    ((((unsigned)(iy0 - 2 + (LY)) < (unsigned)H_) &&                            \
      ((unsigned)(ix0 - 2 + (LX)) < (unsigned)W_))                              \
         ? (dot4(a0, R0) + dot4(a1, R1) + dot4(a2, R2) + dot4(a3, R3)) : 0.f)

        LDX(A0, A1, A2, A3, ly0, lx0)
        LDX(B0, B1, B2, B3, ly1, lx1)
        LDX(C0, C1, C2, C3, ly2, lx2)
        const float D0 = CMP(A0, A1, A2, A3, ly0, lx0); LDX(A0, A1, A2, A3, ly3, lx3)
        const float D1 = CMP(B0, B1, B2, B3, ly1, lx1); LDX(B0, B1, B2, B3, ly4, lx4)
        const float D2 = CMP(C0, C1, C2, C3, ly2, lx2); LDX(C0, C1, C2, C3, ly5, lx5)
        const float D3 = CMP(A0, A1, A2, A3, ly3, lx3); LDX(A0, A1, A2, A3, ly6, lx6)
        const float D4 = CMP(B0, B1, B2, B3, ly4, lx4); LDX(B0, B1, B2, B3, ly7, lx7)
        const float D5 = CMP(C0, C1, C2, C3, ly5, lx5); LDX(C0, C1, C2, C3, ly8, lx8)
        const float D6 = CMP(A0, A1, A2, A3, ly6, lx6);
        const float D7 = CMP(B0, B1, B2, B3, ly7, lx7);
        const float D8 = CMP(C0, C1, C2, C3, ly8, lx8);
#undef BPTR
#undef LDX
#undef CMP

        // Deferred reductions: 9 independent VALU-only DPP butterflies.
        float t;
        t = dpp_add16(D0); if (cgrp == 0) Dsh[wv][0 * 4 + sgrp] = t;
        t = dpp_add16(D1); if (cgrp == 0) Dsh[wv][1 * 4 + sgrp] = t;
        t = dpp_add16(D2); if (cgrp == 0) Dsh[wv][2 * 4 + sgrp] = t;
        t = dpp_add16(D3); if (cgrp == 0) Dsh[wv][3 * 4 + sgrp] = t;
        t = dpp_add16(D4); if (cgrp == 0) Dsh[wv][4 * 4 + sgrp] = t;
        t = dpp_add16(D5); if (cgrp == 0) Dsh[wv][5 * 4 + sgrp] = t;
        t = dpp_add16(D6); if (cgrp == 0) Dsh[wv][6 * 4 + sgrp] = t;
        t = dpp_add16(D7); if (cgrp == 0) Dsh[wv][7 * 4 + sgrp] = t;
        t = dpp_add16(D8); if (cgrp == 0) Dsh[wv][8 * 4 + sgrp] = t;
        __builtin_amdgcn_wave_barrier();   // Dsh writes before same-wave reads

        float cv = 0.f;
        if (lane < 25) {
            const int i = lane / 5, j = lane - i * 5;   // i -> dy, j -> dx
            const float D00 = Dsh[wv][i * 6 + j];
            const float D01 = Dsh[wv][i * 6 + j + 1];
            const float D10 = Dsh[wv][i * 6 + j + 6];
            const float D11 = Dsh[wv][i * 6 + j + 7];
            cv = (1.f - wx) * (1.f - wy) * D00 + wx * (1.f - wy) * D01
               + (1.f - wx) * wy * D10 + wx * wy * D11;
            out[OFF_CV + (size_t)pix * 25 + lane] = cv;
        }

        // WTA: max with first-occurrence tie-break (matches np/jnp argmax).
        float v  = (lane < 25) ? cv : -3.4e38f;
        int  idx = (lane < 25) ? lane : 25;
        #pragma unroll
        for (int off = 16; off >= 1; off >>= 1) {
            const float v2 = __shfl_down(v, off, 32);
            const int   i2 = __shfl_down(idx, off, 32);
            if (v2 > v || (v2 == v && i2 < idx)) { v = v2; idx = i2; }
        }
        if (lane == 0) {
            out[OFF_VAL + pix] = v;
            out[OFF_XY + pix]        = (float)(idx % 5);   // x
            out[OFF_XY + NPIX + pix] = (float)(idx / 5);   // y
        }
        __builtin_amdgcn_wave_barrier();   // next iter's Dsh writes stay behind reads
    }
}

// ---------------------------------------------------------------------------
extern "C" void kernel_launch(void* const* d_in, const int* in_sizes, int n_in,
                              void* d_out, int out_size, void* d_ws, size_t ws_size,
                              hipStream_t stream) {
    const float* flow = (const float*)d_in[0];
    const float* f1   = (const float*)d_in[1];
    const float* f2   = (const float*)d_in[2];
    float* out = (float*)d_out;

    float* f2t = (float*)d_ws;                       // [N, HW, C]

    transpose_f2<<<dim3(HW_ / 64, C_ / 64, N_), 256, 0, stream>>>(f2, f2t);
    costvol_kernel<<<dim3(NBLK), 256, 0, stream>>>(flow, f1, f2t, out);
}